// Round 9
// baseline (579.757 us; speedup 1.0000x reference)
//
#include <hip/hip_runtime.h>
#include <hip/hip_bf16.h>
#include <math.h>

#define NB 16
#define NP 4096
#define DDIM 768
#define MTOT (NB*NP)     // 65536
#define N1 1536
#define SCALEF 0.015625f // 4096^-0.5
#define LNEPS 1e-5f

typedef __attribute__((ext_vector_type(8))) short bf16x8;
typedef __attribute__((ext_vector_type(4))) float f32x4;
typedef __attribute__((ext_vector_type(4))) unsigned int u32x4;
typedef unsigned short us;

__device__ __forceinline__ us f2b(float f){
  union { float f; unsigned int u; } v; v.f = f;
  unsigned int u = v.u;
  unsigned int r = (u + 0x7FFFu + ((u >> 16) & 1u)) >> 16; // RNE
  return (us)r;
}
__device__ __forceinline__ unsigned int pack2(float a, float b){
  return (unsigned int)f2b(a) | ((unsigned int)f2b(b) << 16);
}
__device__ __forceinline__ float b2f(us h){
  union { unsigned int u; float f; } v; v.u = ((unsigned int)h) << 16;
  return v.f;
}
__device__ __forceinline__ float b2f_lo(unsigned int u){
  union { unsigned int x; float f; } v; v.x = u << 16; return v.f;
}
__device__ __forceinline__ float b2f_hi(unsigned int u){
  union { unsigned int x; float f; } v; v.x = u & 0xFFFF0000u; return v.f;
}

typedef __attribute__((address_space(1))) const unsigned int gas_u32;
typedef __attribute__((address_space(3))) unsigned int las_u32;
__device__ __forceinline__ void gl2lds16(const void* g, void* l){
  __builtin_amdgcn_global_load_lds((gas_u32*)g, (las_u32*)l, 16, 0, 0);
}

// ---------------- convert x (f32) -> xb (bf16)
__global__ __launch_bounds__(256) void convert_x(const float* __restrict__ x,
                                                 us* __restrict__ xb){
  size_t i = ((size_t)blockIdx.x * 256 + threadIdx.x) * 8;
  const float4* s = reinterpret_cast<const float4*>(x + i);
  float4 a = s[0], b = s[1];
  u32x4 w;
  w[0] = pack2(a.x, a.y); w[1] = pack2(a.z, a.w);
  w[2] = pack2(b.x, b.y); w[3] = pack2(b.z, b.w);
  *reinterpret_cast<u32x4*>(xb + i) = w;
}

// ---------------- prep: Wt1[n][k] = [wq|wk]^T (bf16), Wt2[n][k] = w_proj^T (bf16)
__global__ __launch_bounds__(256) void prep_w(const float* __restrict__ wq,
                                              const float* __restrict__ wk,
                                              const float* __restrict__ wp,
                                              us* __restrict__ wt1,
                                              us* __restrict__ wt2){
  int idx = blockIdx.x * 256 + threadIdx.x;
  const int tot1 = N1 * DDIM;
  if (idx < tot1){
    int n = idx / DDIM, k = idx % DDIM;
    float v = (n < DDIM) ? wq[k * DDIM + n] : wk[k * DDIM + (n - DDIM)];
    wt1[idx] = f2b(v);
  }
  int idx2 = idx - tot1;
  if (idx2 >= 0 && idx2 < DDIM * DDIM){
    int n = idx2 / DDIM, k = idx2 % DDIM;
    wt2[idx2] = f2b(wp[k * DDIM + n]);
  }
}

// ---------------- prep_wb: wbuf[b][n][d] = bf16( g[b][d] * w_proj[d][n] )
__global__ __launch_bounds__(256) void prep_wb(const us* __restrict__ wt2,
                                               const float* __restrict__ g,
                                               us* __restrict__ wbuf){
  size_t idx = (size_t)blockIdx.x * 256 + threadIdx.x;
  int d = (int)(idx % DDIM);
  size_t nd = idx / DDIM;
  int n = (int)(nd % DDIM);
  int b = (int)(nd / DDIM);
  float v = b2f(wt2[n * DDIM + d]) * g[(size_t)b * DDIM + d];
  wbuf[idx] = f2b(v);
}

// ---------------- ln_reduce: rstats from 6 col-block partials per row
__global__ __launch_bounds__(256) void ln_reduce(const float* __restrict__ lnS,
                                                 const float* __restrict__ lnQ,
                                                 float2* __restrict__ rstats){
  int r = blockIdx.x * 256 + threadIdx.x;
  float s = 0.f, q = 0.f;
  #pragma unroll
  for (int kb = 0; kb < 6; ++kb){
    s += lnS[(size_t)kb * MTOT + r];
    q += lnQ[(size_t)kb * MTOT + r];
  }
  float mu = s * (1.0f / DDIM);
  float var = q * (1.0f / DDIM) - mu * mu;
  rstats[r] = make_float2(mu, rsqrtf(var + LNEPS));
}

// ================ 128x128 4-wave GEMM core, 64 KB LDS -> 2 blocks/CU ========
// R8 lesson: every schedule at 1 block/CU lands at ~240us (latency exposure,
// nothing co-resident). This core: A/B double-buffer 4x16KB = 64 KB, 256 thr
// (4 waves, each 64x64 out), single {vmcnt(0); barrier} per kt; XOR bank
// swizzle (proven 0-conflict in R7 ablation); swapped-operand MFMA (R8) so
// C is (row=..+lr, col=..+lh*4+r) -> packed epilogues. 2 blocks/CU restores
// cross-block latency overlap (m114).
__device__ __forceinline__ void gemm128_core(const us* __restrict__ Ag,
                                             const us* __restrict__ Bg,
                                             us* lds, int t,
                                             f32x4 (&acc)[4][4]){
  us* ldsA = lds;            // [2][128][64] us (16 KB per buf)
  us* ldsB = lds + 16384;    // [2][128][64] us
  const int lane = t & 63, wave = t >> 6;
  const int wm = wave >> 1, wn = wave & 1;
  const int lr = lane & 15, lh = lane >> 4;
  const int srow8 = t >> 3;             // 0..31 within j-chunk
  const int scell = (t & 7) ^ ((t >> 3) & 7);
  const int key8 = lane & 7;

  auto stage_all = [&](int kt){
    int pb = (kt & 1) << 13;            // 8192 us per parity buf
    int ko = kt * 64;
    #pragma unroll
    for (int j = 0; j < 4; ++j){
      int row = j * 32 + srow8;
      gl2lds16(Ag + (size_t)row * DDIM + ko + scell * 8,
               ldsA + pb + j * 2048 + t * 8);
      gl2lds16(Bg + (size_t)row * DDIM + ko + scell * 8,
               ldsB + pb + j * 2048 + t * 8);
    }
  };

  stage_all(0);

  bf16x8 av[4], bv[4];
  for (int kt = 0; kt < 12; ++kt){
    asm volatile("s_waitcnt vmcnt(0)" ::: "memory");
    __builtin_amdgcn_sched_barrier(0);
    __builtin_amdgcn_s_barrier();
    if (kt < 11) stage_all(kt + 1);

    const int pb = (kt & 1) << 13;
    const us* Ab = ldsA + pb;
    const us* Bb = ldsB + pb;
    #pragma unroll
    for (int kk = 0; kk < 2; ++kk){
      #pragma unroll
      for (int fm = 0; fm < 4; ++fm)
        av[fm] = *reinterpret_cast<const bf16x8*>(
            &Ab[(wm*64 + fm*16 + lr)*64 + ((((kk<<2)|lh) ^ key8) << 3)]);
      #pragma unroll
      for (int fn = 0; fn < 4; ++fn)
        bv[fn] = *reinterpret_cast<const bf16x8*>(
            &Bb[(wn*64 + fn*16 + lr)*64 + ((((kk<<2)|lh) ^ key8) << 3)]);
      #pragma unroll
      for (int fm = 0; fm < 4; ++fm)
        #pragma unroll
        for (int fn = 0; fn < 4; ++fn)
          acc[fm][fn] = __builtin_amdgcn_mfma_f32_16x16x32_bf16(
              bv[fn], av[fm], acc[fm][fn], 0, 0, 0);   // swapped: row=lr, col=lh*4+r
    }
  }
  __builtin_amdgcn_s_barrier();   // protect epilogue LDS reuse
}

// ---------------- GEMM1: [q|k] = xb @ wt1^T + bias
__global__ __launch_bounds__(256, 2) void gemm_qk(
    const us* __restrict__ xb, const us* __restrict__ wt1,
    const float* __restrict__ bq, const float* __restrict__ bk,
    const float* __restrict__ w_g,
    us* __restrict__ kout,
    float* __restrict__ qwp, float* __restrict__ qsp, float* __restrict__ ksp,
    float* __restrict__ lnS, float* __restrict__ lnQ)
{
  extern __shared__ us lds[];
  int bid = blockIdx.x;
  int swz = (bid & 7) * ((int)gridDim.x >> 3) + (bid >> 3);
  int bn = swz % 12, bm = swz / 12;   // n fastest: A-panel L2-shared per XCD chunk
  int m0 = bm * 128, n0 = bn * 128;
  int t = threadIdx.x;

  f32x4 acc[4][4] = {};
  gemm128_core(xb + (size_t)m0 * DDIM, wt1 + (size_t)n0 * DDIM, lds, t, acc);

  int lane = t & 63, wave = t >> 6;
  int wm = wave >> 1, wn = wave & 1;
  int lr = lane & 15, lh = lane >> 4;
  bool is_q = (n0 < DDIM);
  int b = m0 >> 12, mc = (m0 & (NP-1)) >> 7;

  float4 bias4[4];
  #pragma unroll
  for (int fn = 0; fn < 4; ++fn){
    int col = wn*64 + fn*16 + lh*4;
    bias4[fn] = *reinterpret_cast<const float4*>(
        is_q ? &bq[n0 + col] : &bk[n0 - DDIM + col]);
  }

  // 128x128 bf16 tile -> LDS (swizzled, packed b64: row=..+lr, 4 cols/lane)
  #pragma unroll
  for (int fm = 0; fm < 4; ++fm){
    int row = wm*64 + fm*16 + lr;
    #pragma unroll
    for (int fn = 0; fn < 4; ++fn){
      int col = wn*64 + fn*16 + lh*4;
      uint2 w;
      w.x = pack2(acc[fm][fn][0] + bias4[fn].x, acc[fm][fn][1] + bias4[fn].y);
      w.y = pack2(acc[fm][fn][2] + bias4[fn].z, acc[fm][fn][3] + bias4[fn].w);
      *reinterpret_cast<uint2*>(&lds[row*128 + (col ^ ((row & 7) << 3))]) = w;
    }
  }
  __syncthreads();

  // sweep (b128): coalesced k-store + column partials (+LN row partials)
  int c8 = t & 15, rb = t >> 4;
  float cp[8] = {0,0,0,0,0,0,0,0};
  float cpw[8] = {0,0,0,0,0,0,0,0};
  float rs8[8], rq8[8];
  #pragma unroll
  for (int s = 0; s < 8; ++s){
    int row = s*16 + rb;
    u32x4 ch = *reinterpret_cast<const u32x4*>(&lds[row*128 + ((c8 ^ (row & 7)) << 3)]);
    float v[8];
    #pragma unroll
    for (int i = 0; i < 4; ++i){ v[2*i] = b2f_lo(ch[i]); v[2*i+1] = b2f_hi(ch[i]); }
    if (is_q){
      float wg = w_g[(m0 & (NP-1)) + row];
      #pragma unroll
      for (int j = 0; j < 8; ++j){ cp[j] += v[j]; cpw[j] += wg * v[j]; }
    } else {
      *reinterpret_cast<u32x4*>(kout + (size_t)(m0+row)*DDIM + (n0 - DDIM) + c8*8) = ch;
      float ss = 0.f, qq = 0.f;
      #pragma unroll
      for (int j = 0; j < 8; ++j){ cp[j] += v[j]; ss += v[j]; qq += v[j]*v[j]; }
      rs8[s] = ss; rq8[s] = qq;
    }
  }
  // partials live in upper 32 KB (disjoint from 32 KB stash being read)
  float* colP  = reinterpret_cast<float*>(lds + 16384);  // [128][16]
  float* colPw = colP + 2048;                            // [128][16] (q)
  float* rowP  = colP + 4096;                            // [128][16] (k)
  float* rowQ  = colP + 6144;                            // [128][16] (k)
  #pragma unroll
  for (int j = 0; j < 8; ++j){
    colP[(c8*8+j)*16 + rb] = cp[j];
    if (is_q) colPw[(c8*8+j)*16 + rb] = cpw[j];
  }
  if (!is_q){
    #pragma unroll
    for (int s = 0; s < 8; ++s){
      int row = s*16 + rb;
      rowP[row*16 + c8] = rs8[s];
      rowQ[row*16 + c8] = rq8[s];
    }
  }
  __syncthreads();
  if (t < 128){
    float s0 = 0.f;
    #pragma unroll
    for (int i = 0; i < 16; ++i) s0 += colP[t*16 + i];
    size_t base = ((size_t)b * 32 + mc) * DDIM;
    if (is_q){
      float s1 = 0.f;
      #pragma unroll
      for (int i = 0; i < 16; ++i) s1 += colPw[t*16 + i];
      qwp[base + n0 + t] = s1;
      qsp[base + n0 + t] = s0;
    } else {
      ksp[base + (n0 - DDIM) + t] = s0;
      float rs_ = 0.f, rq_ = 0.f;
      #pragma unroll
      for (int i = 0; i < 16; ++i){ rs_ += rowP[t*16 + i]; rq_ += rowQ[t*16 + i]; }
      int kb = bn - 6;
      lnS[(size_t)kb * MTOT + m0 + t] = rs_;
      lnQ[(size_t)kb * MTOT + m0 + t] = rq_;
    }
  }
}

// ---------------- combine: per batch — softmax over d, gating chain, g
__global__ __launch_bounds__(256) void combine(
    const float* __restrict__ qwp, const float* __restrict__ qsp, const float* __restrict__ ksp,
    const float* __restrict__ w_fc, const float* __restrict__ b_fc,
    const float* __restrict__ w_fc2, const float* __restrict__ b_fc2,
    float* __restrict__ g)
{
  __shared__ float smA[DDIM];
  __shared__ float smQM[DDIM];
  __shared__ float smKS[DDIM];
  __shared__ float tmat[12][DDIM];
  __shared__ float red[256];
  __shared__ float wbar[12];
  __shared__ float bbar;
  int b = blockIdx.x, t = threadIdx.x;

  for (int col = t; col < DDIM; col += 256){
    float s0 = 0.f, s1 = 0.f, s2 = 0.f;
    for (int mc = 0; mc < 32; ++mc){
      size_t base = ((size_t)b * 32 + mc) * DDIM + col;
      s0 += qwp[base]; s1 += qsp[base]; s2 += ksp[base];
    }
    smA[col] = s0 * SCALEF;
    smQM[col] = s1 * (1.0f / NP);
    smKS[col] = s2;
  }
  __syncthreads();
  float lmax = -1e30f;
  for (int col = t; col < DDIM; col += 256) lmax = fmaxf(lmax, smA[col]);
  red[t] = lmax; __syncthreads();
  for (int off = 128; off; off >>= 1){
    if (t < off) red[t] = fmaxf(red[t], red[t + off]);
    __syncthreads();
  }
  float mx = red[0];
  __syncthreads();
  float lsum = 0.f;
  for (int col = t; col < DDIM; col += 256){
    float e = __expf(smA[col] - mx);
    smA[col] = e; lsum += e;
  }
  red[t] = lsum; __syncthreads();
  for (int off = 128; off; off >>= 1){
    if (t < off) red[t] += red[t + off];
    __syncthreads();
  }
  float inv = 1.0f / red[0];
  for (int col = t; col < DDIM; col += 256) smA[col] *= inv;

  if (t < 12){
    float s = 0.f;
    for (int j = 0; j < 12; ++j) s += w_fc2[t * 12 + j];
    wbar[t] = s * (1.0f / 12.0f);
  }
  if (t == 12){
    float s = 0.f;
    for (int j = 0; j < 12; ++j) s += b_fc2[j];
    bbar = s * (1.0f / 12.0f);
  }
  __syncthreads();
  for (int idx = t; idx < 12 * DDIM; idx += 256){
    int h = idx / DDIM, j = idx % DDIM;
    float s = b_fc[j];
    const float* qm = &smQM[h * 64];
    #pragma unroll 4
    for (int i = 0; i < 64; ++i) s += qm[i] * w_fc[i * DDIM + j];
    tmat[h][j] = 0.5f * s * (1.0f + erff(s * 0.70710678118654752f));
  }
  __syncthreads();
  for (int p = t; p < DDIM; p += 256){
    float s = bbar;
    #pragma unroll
    for (int m = 0; m < 12; ++m){
      int f = p * 12 + m;                 // torch reshape (b,12,768)->(b,768,12)
      s += tmat[f / DDIM][f % DDIM] * wbar[m];
    }
    float dv = 1.0f / (1.0f + __expf(-s));
    g[(size_t)b * DDIM + p] = smA[p] * smKS[p] * dv;
  }
}

// ---------------- GEMM2: out = k @ (g-scaled w_proj) + b_proj + layernorm(k)
// Epilogue fully register-direct: no LDS round trips, no kin re-stage.
__global__ __launch_bounds__(256, 2) void gemm_out(
    const us* __restrict__ kin, const us* __restrict__ wbuf,
    const float2* __restrict__ rstats,
    const float* __restrict__ bp, const float* __restrict__ gamma,
    const float* __restrict__ beta,
    float* __restrict__ out)
{
  extern __shared__ us lds[];
  int bid = blockIdx.x;
  int swz = (bid & 7) * ((int)gridDim.x >> 3) + (bid >> 3);
  int bn = swz % 6, bm = swz / 6;
  int m0 = bm * 128, n0 = bn * 128;
  int t = threadIdx.x;
  int b = m0 >> 12;

  f32x4 acc[4][4] = {};
  gemm128_core(kin + (size_t)m0 * DDIM,
               wbuf + (size_t)b * DDIM * DDIM + (size_t)n0 * DDIM, lds, t, acc);

  int lane = t & 63, wave = t >> 6;
  int wm = wave >> 1, wn = wave & 1;
  int lr = lane & 15, lh = lane >> 4;

  float2 st2[4];
  #pragma unroll
  for (int fm = 0; fm < 4; ++fm)
    st2[fm] = rstats[m0 + wm*64 + fm*16 + lr];

  #pragma unroll
  for (int fn = 0; fn < 4; ++fn){
    int col = wn*64 + fn*16 + lh*4;
    float4 bpv = *reinterpret_cast<const float4*>(&bp[n0 + col]);
    float4 gmv = *reinterpret_cast<const float4*>(&gamma[n0 + col]);
    float4 btv = *reinterpret_cast<const float4*>(&beta[n0 + col]);
    #pragma unroll
    for (int fm = 0; fm < 4; ++fm){
      int row = wm*64 + fm*16 + lr;
      size_t gbase = (size_t)(m0 + row) * DDIM + n0 + col;
      uint2 kw = *reinterpret_cast<const uint2*>(&kin[gbase]);
      float2 st = st2[fm];
      float4 o;
      o.x = acc[fm][fn][0] + bpv.x + (b2f_lo(kw.x) - st.x) * st.y * gmv.x + btv.x;
      o.y = acc[fm][fn][1] + bpv.y + (b2f_hi(kw.x) - st.x) * st.y * gmv.y + btv.y;
      o.z = acc[fm][fn][2] + bpv.z + (b2f_lo(kw.y) - st.x) * st.y * gmv.z + btv.z;
      o.w = acc[fm][fn][3] + bpv.w + (b2f_hi(kw.y) - st.x) * st.y * gmv.w + btv.w;
      *reinterpret_cast<float4*>(&out[gbase]) = o;   // lh-quad = full 64B sector
    }
  }
}

extern "C" void kernel_launch(void* const* d_in, const int* in_sizes, int n_in,
                              void* d_out, int out_size, void* d_ws, size_t ws_size,
                              hipStream_t stream)
{
  const float* x      = (const float*)d_in[0];
  const float* wq     = (const float*)d_in[1];
  const float* bq     = (const float*)d_in[2];
  const float* wk     = (const float*)d_in[3];
  const float* bk     = (const float*)d_in[4];
  const float* w_g    = (const float*)d_in[5];
  const float* w_fc   = (const float*)d_in[6];
  const float* b_fc   = (const float*)d_in[7];
  const float* w_fc2  = (const float*)d_in[8];
  const float* b_fc2  = (const float*)d_in[9];
  const float* w_proj = (const float*)d_in[10];
  const float* b_proj = (const float*)d_in[11];
  const float* gamma  = (const float*)d_in[12];
  const float* beta   = (const float*)d_in[13];
  float* out = (float*)d_out;

  char* ws = (char*)d_ws;
  us*     xb    = (us*)(ws);                       // 100,663,296 B
  us*     kbuf  = (us*)(ws + 100663296);           // 100,663,296 B
  us*     wt1   = (us*)(ws + 201326592);           //   2,359,296 B
  us*     wt2   = (us*)(ws + 203685888);           //   1,179,648 B
  us*     wbuf  = (us*)(ws + 204865536);           //  18,874,368 B
  float*  qwp   = (float*)(ws + 223739904);        //   1,572,864 B
  float*  qsp   = (float*)(ws + 225312768);        //   1,572,864 B
  float*  ksp   = (float*)(ws + 226885632);        //   1,572,864 B
  float*  lnS   = (float*)(ws + 228458496);        //   1,572,864 B (6 col-blocks)
  float*  lnQ   = (float*)(ws + 230031360);        //   1,572,864 B
  float*  g     = (float*)(ws + 231604224);        //      49,152 B
  float2* rstat = (float2*)(ws + 231653376);       //     524,288 B (~221.4 MiB)

  convert_x<<<dim3(MTOT * DDIM / (256 * 8)), dim3(256), 0, stream>>>(x, xb);
  prep_w<<<dim3((N1 * DDIM + DDIM * DDIM) / 256), dim3(256), 0, stream>>>(wq, wk, w_proj, wt1, wt2);
  gemm_qk<<<dim3((MTOT / 128) * (N1 / 128)), dim3(256), 65536, stream>>>(
      xb, wt1, bq, bk, w_g, kbuf, qwp, qsp, ksp, lnS, lnQ);
  ln_reduce<<<dim3(MTOT / 256), dim3(256), 0, stream>>>(lnS, lnQ, rstat);
  combine<<<dim3(NB), dim3(256), 0, stream>>>(qwp, qsp, ksp, w_fc, b_fc, w_fc2, b_fc2, g);
  prep_wb<<<dim3(NB * DDIM * DDIM / 256), dim3(256), 0, stream>>>(wt2, g, wbuf);
  gemm_out<<<dim3((MTOT / 128) * (DDIM / 128)), dim3(256), 65536, stream>>>(
      kbuf, wbuf, rstat, b_proj, gamma, beta, out);
}

// Round 11
// 513.688 us; speedup vs baseline: 1.1286x; 1.1286x over previous
//
#include <hip/hip_runtime.h>
#include <hip/hip_bf16.h>
#include <math.h>

#define NB 16
#define NP 4096
#define DDIM 768
#define MTOT (NB*NP)     // 65536
#define SCALEF 0.015625f // 4096^-0.5
#define LNEPS 1e-5f

typedef __attribute__((ext_vector_type(8))) short bf16x8;
typedef __attribute__((ext_vector_type(4))) float f32x4;
typedef __attribute__((ext_vector_type(4))) unsigned int u32x4;
typedef unsigned short us;

__device__ __forceinline__ us f2b(float f){
  union { float f; unsigned int u; } v; v.f = f;
  unsigned int u = v.u;
  unsigned int r = (u + 0x7FFFu + ((u >> 16) & 1u)) >> 16; // RNE
  return (us)r;
}
__device__ __forceinline__ unsigned int pack2(float a, float b){
  return (unsigned int)f2b(a) | ((unsigned int)f2b(b) << 16);
}
__device__ __forceinline__ float b2f(us h){
  union { unsigned int u; float f; } v; v.u = ((unsigned int)h) << 16;
  return v.f;
}
__device__ __forceinline__ float b2f_lo(unsigned int u){
  union { unsigned int x; float f; } v; v.x = u << 16; return v.f;
}
__device__ __forceinline__ float b2f_hi(unsigned int u){
  union { unsigned int x; float f; } v; v.x = u & 0xFFFF0000u; return v.f;
}

typedef __attribute__((address_space(1))) const unsigned int gas_u32;
typedef __attribute__((address_space(3))) unsigned int las_u32;
__device__ __forceinline__ void gl2lds16(const void* g, void* l){
  __builtin_amdgcn_global_load_lds((gas_u32*)g, (las_u32*)l, 16, 0, 0);
}

// ---------------- convert x (f32) -> xb (bf16)
__global__ __launch_bounds__(256) void convert_x(const float* __restrict__ x,
                                                 us* __restrict__ xb){
  size_t i = ((size_t)blockIdx.x * 256 + threadIdx.x) * 8;
  const float4* s = reinterpret_cast<const float4*>(x + i);
  float4 a = s[0], b = s[1];
  u32x4 w;
  w[0] = pack2(a.x, a.y); w[1] = pack2(a.z, a.w);
  w[2] = pack2(b.x, b.y); w[3] = pack2(b.z, b.w);
  *reinterpret_cast<u32x4*>(xb + i) = w;
}

// ---------------- prep: wtk[n][k] = wk^T (bf16), wt2[n][k] = w_proj^T (bf16)
__global__ __launch_bounds__(256) void prep_w(const float* __restrict__ wk,
                                              const float* __restrict__ wp,
                                              us* __restrict__ wtk,
                                              us* __restrict__ wt2){
  int idx = blockIdx.x * 256 + threadIdx.x;
  const int tot = DDIM * DDIM;
  if (idx < tot){
    int n = idx / DDIM, k = idx % DDIM;
    wtk[idx] = f2b(wk[k * DDIM + n]);
  }
  int i2 = idx - tot;
  if (i2 >= 0 && i2 < tot){
    int n = i2 / DDIM, k = i2 % DDIM;
    wt2[i2] = f2b(wp[k * DDIM + n]);
  }
}

// ---------------- xred: per-128-row-block column reductions of xb
// xwp[b*32+mc][d] = sum_n w_g[n]*x[n,d];  xsp = plain sum (rows of the block)
__global__ __launch_bounds__(192) void xred(const us* __restrict__ xb,
                                            const float* __restrict__ w_g,
                                            float* __restrict__ xwp,
                                            float* __restrict__ xsp){
  __shared__ float sw[2][DDIM], ss[2][DDIM];
  int blk = blockIdx.x, t = threadIdx.x;
  int cg = (t % 96) * 8;   // col chunk base
  int h = t / 96;          // 0 or 1
  int r0 = blk * 128;
  float accw[8] = {0,0,0,0,0,0,0,0}, accs[8] = {0,0,0,0,0,0,0,0};
  for (int r = h; r < 128; r += 2){
    int row = r0 + r;
    float wg = w_g[row & (NP - 1)];
    bf16x8 v = *reinterpret_cast<const bf16x8*>(xb + (size_t)row * DDIM + cg);
    #pragma unroll
    for (int j = 0; j < 8; ++j){
      float f = b2f((us)v[j]);
      accs[j] += f; accw[j] += wg * f;
    }
  }
  #pragma unroll
  for (int j = 0; j < 8; ++j){ sw[h][cg + j] = accw[j]; ss[h][cg + j] = accs[j]; }
  __syncthreads();
  if (h == 0){
    int b = r0 >> 12, mc = (r0 & (NP - 1)) >> 7;
    size_t base = ((size_t)b * 32 + mc) * DDIM;
    #pragma unroll
    for (int j = 0; j < 8; ++j){
      xwp[base + cg + j] = accw[j] + sw[1][cg + j];
      xsp[base + cg + j] = accs[j] + ss[1][cg + j];
    }
  }
}

// ---------------- xmv: qwv = xw@Wq, qmv = xs@Wq, ksv = xs@Wk  (per batch)
__global__ __launch_bounds__(256) void xmv(const float* __restrict__ xwp,
                                           const float* __restrict__ xsp,
                                           const float* __restrict__ wq,
                                           const float* __restrict__ wk,
                                           float* __restrict__ qwv,
                                           float* __restrict__ qmv,
                                           float* __restrict__ ksv){
  __shared__ float sxw[DDIM], sxs[DDIM];
  __shared__ float pa[2][128], pb_[2][128], pc[2][128];
  int blk = blockIdx.x;            // 96 = 16 batches x 6 d-blocks
  int b = blk / 6, dc = (blk % 6) * 128;
  int t = threadIdx.x;
  for (int col = t; col < DDIM; col += 256){
    float s0 = 0.f, s1 = 0.f;
    for (int mc = 0; mc < 32; ++mc){
      size_t base = ((size_t)b * 32 + mc) * DDIM + col;
      s0 += xwp[base]; s1 += xsp[base];
    }
    sxw[col] = s0; sxs[col] = s1;
  }
  __syncthreads();
  int d = dc + (t & 127), h = t >> 7;
  float aq = 0.f, am = 0.f, ak = 0.f;
  for (int k = h * 384; k < h * 384 + 384; ++k){
    float w1 = wq[(size_t)k * DDIM + d];
    float w2 = wk[(size_t)k * DDIM + d];
    float xw = sxw[k], xs = sxs[k];
    aq += xw * w1; am += xs * w1; ak += xs * w2;
  }
  pa[h][t & 127] = aq; pb_[h][t & 127] = am; pc[h][t & 127] = ak;
  __syncthreads();
  if (h == 0){
    size_t o = (size_t)b * DDIM + d;
    qwv[o] = aq + pa[1][t];
    qmv[o] = am + pb_[1][t];
    ksv[o] = ak + pc[1][t];
  }
}

// ---------------- ln_reduce: rstats from 3 col-block partials per row
__global__ __launch_bounds__(256) void ln_reduce(const float* __restrict__ lnS,
                                                 const float* __restrict__ lnQ,
                                                 float2* __restrict__ rstats){
  int r = blockIdx.x * 256 + threadIdx.x;
  float s = lnS[r] + lnS[MTOT + r] + lnS[2*MTOT + r];
  float q = lnQ[r] + lnQ[MTOT + r] + lnQ[2*MTOT + r];
  float mu = s * (1.0f / DDIM);
  float var = q * (1.0f / DDIM) - mu * mu;
  rstats[r] = make_float2(mu, rsqrtf(var + LNEPS));
}

// ================ 256x256 8-wave GEMM core, ONE barrier per K-tile ==========
// Swapped-operand MFMA (R8-proven): C fragment has row=..+lr (one row/lane),
// col=..+lh*4+r (4 consecutive cols/lane) -> packed epilogues.
__device__ __forceinline__ void gemm256_core(const us* __restrict__ Ag,
                                             const us* __restrict__ Bg,
                                             us* lds, int t,
                                             f32x4 (&acc)[4][4][2]){
  us* ldsA = lds;            // [2][256][64] us
  us* ldsB = lds + 32768;    // [2][256][64] us
  const int wave = t >> 6, lane = t & 63;
  const int wr = wave >> 2, wc = wave & 3, lr = lane & 15, lh = lane >> 4;
  const int srow = t >> 3;
  const int scell = (t & 7) ^ ((t >> 3) & 7);
  const int key8 = lane & 7;

  auto stage_all = [&](int kt){
    int pb = (kt & 1) << 14;
    #pragma unroll
    for (int j = 0; j < 4; ++j){
      const us* sa = Ag + (size_t)(j*64 + srow) * DDIM + kt*64 + scell*8;
      gl2lds16(sa, ldsA + pb + j*4096 + (wave << 9));
    }
    #pragma unroll
    for (int j = 0; j < 4; ++j){
      const us* sb = Bg + (size_t)(j*64 + srow) * DDIM + kt*64 + scell*8;
      gl2lds16(sb, ldsB + pb + j*4096 + (wave << 9));
    }
  };

  stage_all(0);

  bf16x8 av[4][2], bv0[2][2], bv1[2][2];

  for (int kt = 0; kt < 12; ++kt){
    asm volatile("s_waitcnt vmcnt(0)" ::: "memory");
    __builtin_amdgcn_sched_barrier(0);
    __builtin_amdgcn_s_barrier();
    if (kt < 11) stage_all(kt + 1);

    const int pb = (kt & 1) << 14;
    const us* Ab = ldsA + pb;
    const us* Bb = ldsB + pb;

    #pragma unroll
    for (int fm = 0; fm < 4; ++fm){
      int ra = 0*128 + wr*64 + fm*16 + lr;
      #pragma unroll
      for (int kk = 0; kk < 2; ++kk)
        av[fm][kk] = *reinterpret_cast<const bf16x8*>(
            &Ab[ra*64 + ((((kk<<2)|lh) ^ key8) << 3)]);
    }
    #pragma unroll
    for (int fn = 0; fn < 2; ++fn){
      int rb0 = 0*128 + wc*32 + fn*16 + lr;
      int rb1 = 1*128 + wc*32 + fn*16 + lr;
      #pragma unroll
      for (int kk = 0; kk < 2; ++kk){
        bv0[fn][kk] = *reinterpret_cast<const bf16x8*>(
            &Bb[rb0*64 + ((((kk<<2)|lh) ^ key8) << 3)]);
        bv1[fn][kk] = *reinterpret_cast<const bf16x8*>(
            &Bb[rb1*64 + ((((kk<<2)|lh) ^ key8) << 3)]);
      }
    }
    #pragma unroll
    for (int fm = 0; fm < 4; ++fm)
      #pragma unroll
      for (int fn = 0; fn < 2; ++fn)
        #pragma unroll
        for (int kk = 0; kk < 2; ++kk){
          acc[0][fm][fn] = __builtin_amdgcn_mfma_f32_16x16x32_bf16(
              bv0[fn][kk], av[fm][kk], acc[0][fm][fn], 0, 0, 0);
          acc[1][fm][fn] = __builtin_amdgcn_mfma_f32_16x16x32_bf16(
              bv1[fn][kk], av[fm][kk], acc[1][fm][fn], 0, 0, 0);
        }

    #pragma unroll
    for (int fm = 0; fm < 4; ++fm){
      int ra = 1*128 + wr*64 + fm*16 + lr;
      #pragma unroll
      for (int kk = 0; kk < 2; ++kk)
        av[fm][kk] = *reinterpret_cast<const bf16x8*>(
            &Ab[ra*64 + ((((kk<<2)|lh) ^ key8) << 3)]);
    }
    #pragma unroll
    for (int fm = 0; fm < 4; ++fm)
      #pragma unroll
      for (int fn = 0; fn < 2; ++fn)
        #pragma unroll
        for (int kk = 0; kk < 2; ++kk){
          acc[2][fm][fn] = __builtin_amdgcn_mfma_f32_16x16x32_bf16(
              bv0[fn][kk], av[fm][kk], acc[2][fm][fn], 0, 0, 0);
          acc[3][fm][fn] = __builtin_amdgcn_mfma_f32_16x16x32_bf16(
              bv1[fn][kk], av[fm][kk], acc[3][fm][fn], 0, 0, 0);
        }
  }
  __builtin_amdgcn_s_barrier();
}

// ---------------- GEMM-K: k = xb @ wk^T + bk (N=768 only — q eliminated!)
__global__ __launch_bounds__(512, 2) void gemm_k(
    const us* __restrict__ xb, const us* __restrict__ wtk,
    const float* __restrict__ bk,
    us* __restrict__ kout,
    float* __restrict__ lnS, float* __restrict__ lnQ)
{
  extern __shared__ us lds[];
  int bid = blockIdx.x;
  int swz = (bid & 7) * ((int)gridDim.x >> 3) + (bid >> 3);
  int bn = swz % 3, bm = swz / 3;
  int m0 = bm * 256, n0 = bn * 256;
  int t = threadIdx.x;

  f32x4 acc[4][4][2] = {};
  gemm256_core(xb + (size_t)m0 * DDIM, wtk + (size_t)n0 * DDIM, lds, t, acc);

  int wave = t >> 6, lane = t & 63;
  int wr = wave >> 2, wc = wave & 3, lr = lane & 15, lh = lane >> 4;

  float4 bias4[2][2];
  #pragma unroll
  for (int qn = 0; qn < 2; ++qn)
    #pragma unroll
    for (int fn = 0; fn < 2; ++fn){
      int col = qn*128 + wc*32 + fn*16 + lh*4;
      bias4[qn][fn] = *reinterpret_cast<const float4*>(&bk[n0 + col]);
    }

  // 256x256 bf16 tile -> LDS (swizzled, packed b64)
  #pragma unroll
  for (int p = 0; p < 4; ++p){
    int qm = p >> 1, qn = p & 1;
    #pragma unroll
    for (int fm = 0; fm < 4; ++fm){
      int row = qm*128 + wr*64 + fm*16 + lr;
      #pragma unroll
      for (int fn = 0; fn < 2; ++fn){
        int col = qn*128 + wc*32 + fn*16 + lh*4;
        uint2 w;
        w.x = pack2(acc[p][fm][fn][0] + bias4[qn][fn].x,
                    acc[p][fm][fn][1] + bias4[qn][fn].y);
        w.y = pack2(acc[p][fm][fn][2] + bias4[qn][fn].z,
                    acc[p][fm][fn][3] + bias4[qn][fn].w);
        *reinterpret_cast<uint2*>(&lds[row*256 + (col ^ ((row & 7) << 3))]) = w;
      }
    }
  }
  __syncthreads();

  // sweep: coalesced k-store + LN row partials
  int c8 = t & 31, rb = t >> 5;
  float rs16[16], rq16[16];
  #pragma unroll
  for (int s = 0; s < 16; ++s){
    int row = s*16 + rb;
    u32x4 ch = *reinterpret_cast<const u32x4*>(&lds[row*256 + ((c8 ^ (row & 7)) << 3)]);
    *reinterpret_cast<u32x4*>(kout + (size_t)(m0+row)*DDIM + n0 + c8*8) = ch;
    float ss = 0.f, qq = 0.f;
    #pragma unroll
    for (int i = 0; i < 4; ++i){
      float v0 = b2f_lo(ch[i]), v1 = b2f_hi(ch[i]);
      ss += v0 + v1; qq += v0*v0 + v1*v1;
    }
    rs16[s] = ss; rq16[s] = qq;
  }
  __syncthreads();
  float* rowP = reinterpret_cast<float*>(lds);   // [256][32]
  float* rowQ = rowP + 8192;                     // [256][32]
  #pragma unroll
  for (int s = 0; s < 16; ++s){
    int row = s*16 + rb;
    rowP[row*32 + c8] = rs16[s];
    rowQ[row*32 + c8] = rq16[s];
  }
  __syncthreads();
  if (t < 256){
    float rs_ = 0.f, rq_ = 0.f;
    #pragma unroll
    for (int i = 0; i < 32; ++i){ rs_ += rowP[t*32 + i]; rq_ += rowQ[t*32 + i]; }
    lnS[(size_t)bn * MTOT + m0 + t] = rs_;
    lnQ[(size_t)bn * MTOT + m0 + t] = rq_;
  }
}

// ---------------- prep_wb: wbuf[b][n][d] = bf16( g[b][d] * w_proj[d][n] )
__global__ __launch_bounds__(256) void prep_wb(const us* __restrict__ wt2,
                                               const float* __restrict__ g,
                                               us* __restrict__ wbuf){
  size_t idx = (size_t)blockIdx.x * 256 + threadIdx.x;
  int d = (int)(idx % DDIM);
  size_t nd = idx / DDIM;
  int n = (int)(nd % DDIM);
  int b = (int)(nd / DDIM);
  float v = b2f(wt2[n * DDIM + d]) * g[(size_t)b * DDIM + d];
  wbuf[idx] = f2b(v);
}

// ---------------- combine: per batch — softmax + gating chain from matvecs
__global__ __launch_bounds__(256) void combine(
    const float* __restrict__ qwv, const float* __restrict__ qmv,
    const float* __restrict__ ksv,
    const float* __restrict__ bq, const float* __restrict__ bk,
    const float* __restrict__ w_g,
    const float* __restrict__ w_fc, const float* __restrict__ b_fc,
    const float* __restrict__ w_fc2, const float* __restrict__ b_fc2,
    float* __restrict__ g)
{
  __shared__ float smA[DDIM];
  __shared__ float smQM[DDIM];
  __shared__ float smKS[DDIM];
  __shared__ float tmat[12][DDIM];
  __shared__ float red[256];
  __shared__ float wbar[12];
  __shared__ float bbar;
  int b = blockIdx.x, t = threadIdx.x;

  // sum of w_g
  float sw = 0.f;
  for (int i = t; i < NP; i += 256) sw += w_g[i];
  red[t] = sw; __syncthreads();
  for (int off = 128; off; off >>= 1){
    if (t < off) red[t] += red[t + off];
    __syncthreads();
  }
  float sumwg = red[0];
  __syncthreads();

  for (int col = t; col < DDIM; col += 256){
    size_t o = (size_t)b * DDIM + col;
    smA[col]  = (qwv[o] + bq[col] * sumwg) * SCALEF;
    smQM[col] = qmv[o] * (1.0f / NP) + bq[col];
    smKS[col] = ksv[o] + (float)NP * bk[col];
  }
  __syncthreads();

  float lmax = -1e30f;
  for (int col = t; col < DDIM; col += 256) lmax = fmaxf(lmax, smA[col]);
  red[t] = lmax; __syncthreads();
  for (int off = 128; off; off >>= 1){
    if (t < off) red[t] = fmaxf(red[t], red[t + off]);
    __syncthreads();
  }
  float mx = red[0];
  __syncthreads();
  float lsum = 0.f;
  for (int col = t; col < DDIM; col += 256){
    float e = __expf(smA[col] - mx);
    smA[col] = e; lsum += e;
  }
  red[t] = lsum; __syncthreads();
  for (int off = 128; off; off >>= 1){
    if (t < off) red[t] += red[t + off];
    __syncthreads();
  }
  float inv = 1.0f / red[0];
  for (int col = t; col < DDIM; col += 256) smA[col] *= inv;

  if (t < 12){
    float s = 0.f;
    for (int j = 0; j < 12; ++j) s += w_fc2[t * 12 + j];
    wbar[t] = s * (1.0f / 12.0f);
  }
  if (t == 12){
    float s = 0.f;
    for (int j = 0; j < 12; ++j) s += b_fc2[j];
    bbar = s * (1.0f / 12.0f);
  }
  __syncthreads();
  for (int idx = t; idx < 12 * DDIM; idx += 256){
    int h = idx / DDIM, j = idx % DDIM;
    float s = b_fc[j];
    const float* qm = &smQM[h * 64];
    #pragma unroll 4
    for (int i = 0; i < 64; ++i) s += qm[i] * w_fc[i * DDIM + j];
    tmat[h][j] = 0.5f * s * (1.0f + erff(s * 0.70710678118654752f));
  }
  __syncthreads();
  for (int p = t; p < DDIM; p += 256){
    float s = bbar;
    #pragma unroll
    for (int m = 0; m < 12; ++m){
      int f = p * 12 + m;                 // torch reshape (b,12,768)->(b,768,12)
      s += tmat[f / DDIM][f % DDIM] * wbar[m];
    }
    float dv = 1.0f / (1.0f + __expf(-s));
    g[(size_t)b * DDIM + p] = smA[p] * smKS[p] * dv;
  }
}

// ---------------- GEMM2: out = k @ (g-scaled w_proj) + b_proj + layernorm(k)
__global__ __launch_bounds__(512, 2) void gemm_out(
    const us* __restrict__ kin, const us* __restrict__ wbuf,
    const float2* __restrict__ rstats,
    const float* __restrict__ bp, const float* __restrict__ gamma,
    const float* __restrict__ beta,
    float* __restrict__ out)
{
  extern __shared__ us lds[];
  int bid = blockIdx.x;
  int swz = (bid & 7) * ((int)gridDim.x >> 3) + (bid >> 3);
  int bn = swz % 3, bm = swz / 3;
  int m0 = bm * 256, n0 = bn * 256;
  int t = threadIdx.x;
  int b = m0 >> 12;

  f32x4 acc[4][4][2] = {};
  gemm256_core(kin + (size_t)m0 * DDIM,
               wbuf + (size_t)b * DDIM * DDIM + (size_t)n0 * DDIM, lds, t, acc);

  int wave = t >> 6, lane = t & 63;
  int wr = wave >> 2, wc = wave & 3, lr = lane & 15, lh = lane >> 4;

  // stage kin 256x256 tile (swizzled source cells, linear LDS dest)
  #pragma unroll
  for (int j = 0; j < 16; ++j){
    int row = j*16 + (t >> 5);
    const us* src = kin + (size_t)(m0 + row) * DDIM + n0 + (((t & 31) ^ (row & 7)) << 3);
    gl2lds16(src, lds + j*4096 + (wave << 9));
  }
  float2 st2[2][4];
  #pragma unroll
  for (int qm = 0; qm < 2; ++qm)
    #pragma unroll
    for (int fm = 0; fm < 4; ++fm)
      st2[qm][fm] = rstats[m0 + qm*128 + wr*64 + fm*16 + lr];
  asm volatile("s_waitcnt vmcnt(0)" ::: "memory");
  __syncthreads();

  #pragma unroll
  for (int p = 0; p < 4; ++p){
    int qm = p >> 1, qn = p & 1;
    #pragma unroll
    for (int fn = 0; fn < 2; ++fn){
      int col = qn*128 + wc*32 + fn*16 + lh*4;
      float4 bpv = *reinterpret_cast<const float4*>(&bp[n0 + col]);
      float4 gmv = *reinterpret_cast<const float4*>(&gamma[n0 + col]);
      float4 btv = *reinterpret_cast<const float4*>(&beta[n0 + col]);
      #pragma unroll
      for (int fm = 0; fm < 4; ++fm){
        int row = qm*128 + wr*64 + fm*16 + lr;
        uint2 kw = *reinterpret_cast<const uint2*>(&lds[row*256 + (col ^ ((row & 7) << 3))]);
        float2 st = st2[qm][fm];
        acc[p][fm][fn][0] += bpv.x + (b2f_lo(kw.x) - st.x) * st.y * gmv.x + btv.x;
        acc[p][fm][fn][1] += bpv.y + (b2f_hi(kw.x) - st.x) * st.y * gmv.y + btv.y;
        acc[p][fm][fn][2] += bpv.z + (b2f_lo(kw.y) - st.x) * st.y * gmv.z + btv.z;
        acc[p][fm][fn][3] += bpv.w + (b2f_hi(kw.y) - st.x) * st.y * gmv.w + btv.w;
      }
    }
  }
  __syncthreads();

  float* fb = reinterpret_cast<float*>(lds);   // [256][128] f32 = 128 KB
  #pragma unroll
  for (int h = 0; h < 2; ++h){
    #pragma unroll
    for (int qm2 = 0; qm2 < 2; ++qm2){
      int p = qm2*2 + h;
      #pragma unroll
      for (int fm = 0; fm < 4; ++fm){
        int row = qm2*128 + wr*64 + fm*16 + lr;
        #pragma unroll
        for (int fn = 0; fn < 2; ++fn){
          int c = wc*32 + fn*16 + lh*4;
          *reinterpret_cast<f32x4*>(&fb[row*128 + (c ^ ((row & 7) << 2))]) = acc[p][fm][fn];
        }
      }
    }
    __syncthreads();
    #pragma unroll
    for (int s = 0; s < 16; ++s){
      int u = s*512 + t;
      int row = u >> 5, c4 = u & 31;
      float4 vv = *reinterpret_cast<const float4*>(&fb[row*128 + ((c4 ^ (row & 7)) << 2)]);
      *reinterpret_cast<float4*>(&out[(size_t)(m0 + row) * DDIM + n0 + h*128 + c4*4]) = vv;
    }
    __syncthreads();
  }
}

extern "C" void kernel_launch(void* const* d_in, const int* in_sizes, int n_in,
                              void* d_out, int out_size, void* d_ws, size_t ws_size,
                              hipStream_t stream)
{
  const float* x      = (const float*)d_in[0];
  const float* wq     = (const float*)d_in[1];
  const float* bq     = (const float*)d_in[2];
  const float* wk     = (const float*)d_in[3];
  const float* bk     = (const float*)d_in[4];
  const float* w_g    = (const float*)d_in[5];
  const float* w_fc   = (const float*)d_in[6];
  const float* b_fc   = (const float*)d_in[7];
  const float* w_fc2  = (const float*)d_in[8];
  const float* b_fc2  = (const float*)d_in[9];
  const float* w_proj = (const float*)d_in[10];
  const float* b_proj = (const float*)d_in[11];
  const float* gamma  = (const float*)d_in[12];
  const float* beta   = (const float*)d_in[13];
  float* out = (float*)d_out;

  char* ws = (char*)d_ws;
  us*     xb    = (us*)(ws);                       // 100,663,296 B
  us*     kbuf  = (us*)(ws + 100663296);           // 100,663,296 B
  us*     wtk   = (us*)(ws + 201326592);           //   1,179,648 B
  us*     wt2   = (us*)(ws + 202506240);           //   1,179,648 B
  us*     wbuf  = (us*)(ws + 203685888);           //  18,874,368 B
  float*  xwp   = (float*)(ws + 222560256);        //   1,572,864 B
  float*  xsp   = (float*)(ws + 224133120);        //   1,572,864 B
  float*  lnS   = (float*)(ws + 225705984);        //     786,432 B
  float*  lnQ   = (float*)(ws + 226492416);        //     786,432 B
  float*  g     = (float*)(ws + 227278848);        //      49,152 B
  float2* rstat = (float2*)(ws + 227328000);       //     524,288 B
  float*  qwv   = (float*)(ws + 227852288);        //      49,152 B
  float*  qmv   = (float*)(ws + 227901440);        //      49,152 B
  float*  ksv   = (float*)(ws + 227950592);        //      49,152 B (~217.4 MiB)

  convert_x<<<dim3(MTOT * DDIM / (256 * 8)), dim3(256), 0, stream>>>(x, xb);
  prep_w<<<dim3(2 * DDIM * DDIM / 256), dim3(256), 0, stream>>>(wk, w_proj, wtk, wt2);
  xred<<<dim3(MTOT / 128), dim3(192), 0, stream>>>(xb, w_g, xwp, xsp);
  xmv<<<dim3(NB * 6), dim3(256), 0, stream>>>(xwp, xsp, wq, wk, qwv, qmv, ksv);
  gemm_k<<<dim3((MTOT / 256) * 3), dim3(512), 131072, stream>>>(
      xb, wtk, bk, kbuf, lnS, lnQ);
  ln_reduce<<<dim3(MTOT / 256), dim3(256), 0, stream>>>(lnS, lnQ, rstat);
  combine<<<dim3(NB), dim3(256), 0, stream>>>(
      qwv, qmv, ksv, bq, bk, w_g, w_fc, b_fc, w_fc2, b_fc2, g);
  prep_wb<<<dim3(NB * DDIM * DDIM / 256), dim3(256), 0, stream>>>(wt2, g, wbuf);
  gemm_out<<<dim3((MTOT / 256) * 3), dim3(512), 131072, stream>>>(
      kbuf, wbuf, rstat, b_proj, gamma, beta, out);
}

// Round 12
// 473.235 us; speedup vs baseline: 1.2251x; 1.0855x over previous
//
#include <hip/hip_runtime.h>
#include <hip/hip_bf16.h>
#include <math.h>

#define NB 16
#define NP 4096
#define DDIM 768
#define MTOT (NB*NP)     // 65536
#define SCALEF 0.015625f // 4096^-0.5
#define LNEPS 1e-5f

typedef __attribute__((ext_vector_type(8))) short bf16x8;
typedef __attribute__((ext_vector_type(4))) float f32x4;
typedef __attribute__((ext_vector_type(4))) unsigned int u32x4;
typedef unsigned short us;

__device__ __forceinline__ us f2b(float f){
  union { float f; unsigned int u; } v; v.f = f;
  unsigned int u = v.u;
  unsigned int r = (u + 0x7FFFu + ((u >> 16) & 1u)) >> 16; // RNE
  return (us)r;
}
__device__ __forceinline__ unsigned int pack2(float a, float b){
  return (unsigned int)f2b(a) | ((unsigned int)f2b(b) << 16);
}
__device__ __forceinline__ float b2f(us h){
  union { unsigned int u; float f; } v; v.u = ((unsigned int)h) << 16;
  return v.f;
}
__device__ __forceinline__ float b2f_lo(unsigned int u){
  union { unsigned int x; float f; } v; v.x = u << 16; return v.f;
}
__device__ __forceinline__ float b2f_hi(unsigned int u){
  union { unsigned int x; float f; } v; v.x = u & 0xFFFF0000u; return v.f;
}

typedef __attribute__((address_space(1))) const unsigned int gas_u32;
typedef __attribute__((address_space(3))) unsigned int las_u32;
__device__ __forceinline__ void gl2lds16(const void* g, void* l){
  __builtin_amdgcn_global_load_lds((gas_u32*)g, (las_u32*)l, 16, 0, 0);
}

// ---------------- convert x (f32) -> xb (bf16), FUSED with column reductions
// (R11 xred eliminated: same 201 MB stream now also emits xwp/xsp partials).
// Block = 128 rows; 384 thr: col-chunk c = t%96 (8 cols), row-group g = t/4? no:
// g = t/96 (rows g, g+4, ..., 32 rows/thread).
__global__ __launch_bounds__(384) void convert_x(const float* __restrict__ x,
                                                 const float* __restrict__ w_g,
                                                 us* __restrict__ xb,
                                                 float* __restrict__ xwp,
                                                 float* __restrict__ xsp){
  __shared__ float sw[4][DDIM], ss[4][DDIM];
  int blk = blockIdx.x, t = threadIdx.x;
  int c = t % 96, g = t / 96;
  int cg = c * 8;
  int r0 = blk * 128;
  float accw[8] = {0,0,0,0,0,0,0,0}, accs[8] = {0,0,0,0,0,0,0,0};
  for (int r = g; r < 128; r += 4){
    int row = r0 + r;
    float wg = w_g[row & (NP - 1)];
    const float4* s = reinterpret_cast<const float4*>(x + (size_t)row * DDIM + cg);
    float4 a = s[0], b = s[1];
    u32x4 w;
    w[0] = pack2(a.x, a.y); w[1] = pack2(a.z, a.w);
    w[2] = pack2(b.x, b.y); w[3] = pack2(b.z, b.w);
    *reinterpret_cast<u32x4*>(xb + (size_t)row * DDIM + cg) = w;
    float v[8] = {a.x, a.y, a.z, a.w, b.x, b.y, b.z, b.w};
    #pragma unroll
    for (int j = 0; j < 8; ++j){ accs[j] += v[j]; accw[j] += wg * v[j]; }
  }
  #pragma unroll
  for (int j = 0; j < 8; ++j){ sw[g][cg + j] = accw[j]; ss[g][cg + j] = accs[j]; }
  __syncthreads();
  if (g == 0){
    int b = r0 >> 12, mc = (r0 & (NP - 1)) >> 7;
    size_t base = ((size_t)b * 32 + mc) * DDIM;
    #pragma unroll
    for (int j = 0; j < 8; ++j){
      xwp[base + cg + j] = accw[j] + sw[1][cg + j] + sw[2][cg + j] + sw[3][cg + j];
      xsp[base + cg + j] = accs[j] + ss[1][cg + j] + ss[2][cg + j] + ss[3][cg + j];
    }
  }
}

// ---------------- prep: wtk[n][k] = wk^T (bf16), wt2[n][k] = w_proj^T (bf16)
__global__ __launch_bounds__(256) void prep_w(const float* __restrict__ wk,
                                              const float* __restrict__ wp,
                                              us* __restrict__ wtk,
                                              us* __restrict__ wt2){
  int idx = blockIdx.x * 256 + threadIdx.x;
  const int tot = DDIM * DDIM;
  if (idx < tot){
    int n = idx / DDIM, k = idx % DDIM;
    wtk[idx] = f2b(wk[k * DDIM + n]);
  }
  int i2 = idx - tot;
  if (i2 >= 0 && i2 < tot){
    int n = i2 / DDIM, k = i2 % DDIM;
    wt2[i2] = f2b(wp[k * DDIM + n]);
  }
}

// ---------------- xmv: qwv = xw@Wq, qmv = xs@Wq, ksv = xs@Wk  (per batch)
__global__ __launch_bounds__(256) void xmv(const float* __restrict__ xwp,
                                           const float* __restrict__ xsp,
                                           const float* __restrict__ wq,
                                           const float* __restrict__ wk,
                                           float* __restrict__ qwv,
                                           float* __restrict__ qmv,
                                           float* __restrict__ ksv){
  __shared__ float sxw[DDIM], sxs[DDIM];
  __shared__ float pa[2][128], pb_[2][128], pc[2][128];
  int blk = blockIdx.x;            // 96 = 16 batches x 6 d-blocks
  int b = blk / 6, dc = (blk % 6) * 128;
  int t = threadIdx.x;
  for (int col = t; col < DDIM; col += 256){
    float s0 = 0.f, s1 = 0.f;
    for (int mc = 0; mc < 32; ++mc){
      size_t base = ((size_t)b * 32 + mc) * DDIM + col;
      s0 += xwp[base]; s1 += xsp[base];
    }
    sxw[col] = s0; sxs[col] = s1;
  }
  __syncthreads();
  int d = dc + (t & 127), h = t >> 7;
  float aq = 0.f, am = 0.f, ak = 0.f;
  for (int k = h * 384; k < h * 384 + 384; ++k){
    float w1 = wq[(size_t)k * DDIM + d];
    float w2 = wk[(size_t)k * DDIM + d];
    float xw = sxw[k], xs = sxs[k];
    aq += xw * w1; am += xs * w1; ak += xs * w2;
  }
  pa[h][t & 127] = aq; pb_[h][t & 127] = am; pc[h][t & 127] = ak;
  __syncthreads();
  if (h == 0){
    size_t o = (size_t)b * DDIM + d;
    qwv[o] = aq + pa[1][t];
    qmv[o] = am + pb_[1][t];
    ksv[o] = ak + pc[1][t];
  }
}

// ---------------- ln_reduce: rstats from 3 col-block partials per row
__global__ __launch_bounds__(256) void ln_reduce(const float* __restrict__ lnS,
                                                 const float* __restrict__ lnQ,
                                                 float2* __restrict__ rstats){
  int r = blockIdx.x * 256 + threadIdx.x;
  float s = lnS[r] + lnS[MTOT + r] + lnS[2*MTOT + r];
  float q = lnQ[r] + lnQ[MTOT + r] + lnQ[2*MTOT + r];
  float mu = s * (1.0f / DDIM);
  float var = q * (1.0f / DDIM) - mu * mu;
  rstats[r] = make_float2(mu, rsqrtf(var + LNEPS));
}

// ================ 256x256 8-wave GEMM core, ONE barrier per K-tile ==========
// Swapped-operand MFMA (R8-proven). R12 change: sched_barrier moved AFTER
// s_barrier — still fences stage/ds_reads from hoisting above the barrier,
// but lets kt-1's register-only MFMA tail sink into the vmcnt+barrier wait
// (m141: pinning the boundary above the wait costs up to 1.7x).
__device__ __forceinline__ void gemm256_core(const us* __restrict__ Ag,
                                             const us* __restrict__ Bg,
                                             us* lds, int t,
                                             f32x4 (&acc)[4][4][2]){
  us* ldsA = lds;            // [2][256][64] us
  us* ldsB = lds + 32768;    // [2][256][64] us
  const int wave = t >> 6, lane = t & 63;
  const int wr = wave >> 2, wc = wave & 3, lr = lane & 15, lh = lane >> 4;
  const int srow = t >> 3;
  const int scell = (t & 7) ^ ((t >> 3) & 7);
  const int key8 = lane & 7;

  auto stage_all = [&](int kt){
    int pb = (kt & 1) << 14;
    #pragma unroll
    for (int j = 0; j < 4; ++j){
      const us* sa = Ag + (size_t)(j*64 + srow) * DDIM + kt*64 + scell*8;
      gl2lds16(sa, ldsA + pb + j*4096 + (wave << 9));
    }
    #pragma unroll
    for (int j = 0; j < 4; ++j){
      const us* sb = Bg + (size_t)(j*64 + srow) * DDIM + kt*64 + scell*8;
      gl2lds16(sb, ldsB + pb + j*4096 + (wave << 9));
    }
  };

  stage_all(0);

  bf16x8 av[4][2], bv0[2][2], bv1[2][2];

  for (int kt = 0; kt < 12; ++kt){
    asm volatile("s_waitcnt vmcnt(0)" ::: "memory");
    __builtin_amdgcn_s_barrier();
    __builtin_amdgcn_sched_barrier(0);
    if (kt < 11) stage_all(kt + 1);

    const int pb = (kt & 1) << 14;
    const us* Ab = ldsA + pb;
    const us* Bb = ldsB + pb;

    #pragma unroll
    for (int fm = 0; fm < 4; ++fm){
      int ra = 0*128 + wr*64 + fm*16 + lr;
      #pragma unroll
      for (int kk = 0; kk < 2; ++kk)
        av[fm][kk] = *reinterpret_cast<const bf16x8*>(
            &Ab[ra*64 + ((((kk<<2)|lh) ^ key8) << 3)]);
    }
    #pragma unroll
    for (int fn = 0; fn < 2; ++fn){
      int rb0 = 0*128 + wc*32 + fn*16 + lr;
      int rb1 = 1*128 + wc*32 + fn*16 + lr;
      #pragma unroll
      for (int kk = 0; kk < 2; ++kk){
        bv0[fn][kk] = *reinterpret_cast<const bf16x8*>(
            &Bb[rb0*64 + ((((kk<<2)|lh) ^ key8) << 3)]);
        bv1[fn][kk] = *reinterpret_cast<const bf16x8*>(
            &Bb[rb1*64 + ((((kk<<2)|lh) ^ key8) << 3)]);
      }
    }
    #pragma unroll
    for (int fm = 0; fm < 4; ++fm)
      #pragma unroll
      for (int fn = 0; fn < 2; ++fn)
        #pragma unroll
        for (int kk = 0; kk < 2; ++kk){
          acc[0][fm][fn] = __builtin_amdgcn_mfma_f32_16x16x32_bf16(
              bv0[fn][kk], av[fm][kk], acc[0][fm][fn], 0, 0, 0);
          acc[1][fm][fn] = __builtin_amdgcn_mfma_f32_16x16x32_bf16(
              bv1[fn][kk], av[fm][kk], acc[1][fm][fn], 0, 0, 0);
        }

    #pragma unroll
    for (int fm = 0; fm < 4; ++fm){
      int ra = 1*128 + wr*64 + fm*16 + lr;
      #pragma unroll
      for (int kk = 0; kk < 2; ++kk)
        av[fm][kk] = *reinterpret_cast<const bf16x8*>(
            &Ab[ra*64 + ((((kk<<2)|lh) ^ key8) << 3)]);
    }
    #pragma unroll
    for (int fm = 0; fm < 4; ++fm)
      #pragma unroll
      for (int fn = 0; fn < 2; ++fn)
        #pragma unroll
        for (int kk = 0; kk < 2; ++kk){
          acc[2][fm][fn] = __builtin_amdgcn_mfma_f32_16x16x32_bf16(
              bv0[fn][kk], av[fm][kk], acc[2][fm][fn], 0, 0, 0);
          acc[3][fm][fn] = __builtin_amdgcn_mfma_f32_16x16x32_bf16(
              bv1[fn][kk], av[fm][kk], acc[3][fm][fn], 0, 0, 0);
        }
  }
  __builtin_amdgcn_s_barrier();
}

// ---------------- GEMM-K: k = xb @ wk^T + bk (N=768 only — q eliminated)
__global__ __launch_bounds__(512, 2) void gemm_k(
    const us* __restrict__ xb, const us* __restrict__ wtk,
    const float* __restrict__ bk,
    us* __restrict__ kout,
    float* __restrict__ lnS, float* __restrict__ lnQ)
{
  extern __shared__ us lds[];
  int bid = blockIdx.x;
  int swz = (bid & 7) * ((int)gridDim.x >> 3) + (bid >> 3);
  int bn = swz % 3, bm = swz / 3;
  int m0 = bm * 256, n0 = bn * 256;
  int t = threadIdx.x;

  f32x4 acc[4][4][2] = {};
  gemm256_core(xb + (size_t)m0 * DDIM, wtk + (size_t)n0 * DDIM, lds, t, acc);

  int wave = t >> 6, lane = t & 63;
  int wr = wave >> 2, wc = wave & 3, lr = lane & 15, lh = lane >> 4;

  float4 bias4[2][2];
  #pragma unroll
  for (int qn = 0; qn < 2; ++qn)
    #pragma unroll
    for (int fn = 0; fn < 2; ++fn){
      int col = qn*128 + wc*32 + fn*16 + lh*4;
      bias4[qn][fn] = *reinterpret_cast<const float4*>(&bk[n0 + col]);
    }

  // 256x256 bf16 tile -> LDS (swizzled, packed b64)
  #pragma unroll
  for (int p = 0; p < 4; ++p){
    int qm = p >> 1, qn = p & 1;
    #pragma unroll
    for (int fm = 0; fm < 4; ++fm){
      int row = qm*128 + wr*64 + fm*16 + lr;
      #pragma unroll
      for (int fn = 0; fn < 2; ++fn){
        int col = qn*128 + wc*32 + fn*16 + lh*4;
        uint2 w;
        w.x = pack2(acc[p][fm][fn][0] + bias4[qn][fn].x,
                    acc[p][fm][fn][1] + bias4[qn][fn].y);
        w.y = pack2(acc[p][fm][fn][2] + bias4[qn][fn].z,
                    acc[p][fm][fn][3] + bias4[qn][fn].w);
        *reinterpret_cast<uint2*>(&lds[row*256 + (col ^ ((row & 7) << 3))]) = w;
      }
    }
  }
  __syncthreads();

  // sweep: coalesced k-store + LN row partials
  int c8 = t & 31, rb = t >> 5;
  float rs16[16], rq16[16];
  #pragma unroll
  for (int s = 0; s < 16; ++s){
    int row = s*16 + rb;
    u32x4 ch = *reinterpret_cast<const u32x4*>(&lds[row*256 + ((c8 ^ (row & 7)) << 3)]);
    *reinterpret_cast<u32x4*>(kout + (size_t)(m0+row)*DDIM + n0 + c8*8) = ch;
    float ss = 0.f, qq = 0.f;
    #pragma unroll
    for (int i = 0; i < 4; ++i){
      float v0 = b2f_lo(ch[i]), v1 = b2f_hi(ch[i]);
      ss += v0 + v1; qq += v0*v0 + v1*v1;
    }
    rs16[s] = ss; rq16[s] = qq;
  }
  __syncthreads();
  float* rowP = reinterpret_cast<float*>(lds);   // [256][32]
  float* rowQ = rowP + 8192;                     // [256][32]
  #pragma unroll
  for (int s = 0; s < 16; ++s){
    int row = s*16 + rb;
    rowP[row*32 + c8] = rs16[s];
    rowQ[row*32 + c8] = rq16[s];
  }
  __syncthreads();
  if (t < 256){
    float rs_ = 0.f, rq_ = 0.f;
    #pragma unroll
    for (int i = 0; i < 32; ++i){ rs_ += rowP[t*32 + i]; rq_ += rowQ[t*32 + i]; }
    lnS[(size_t)bn * MTOT + m0 + t] = rs_;
    lnQ[(size_t)bn * MTOT + m0 + t] = rq_;
  }
}

// ---------------- prep_wb: wbuf[b][n][d] = bf16( g[b][d] * w_proj[d][n] )
__global__ __launch_bounds__(256) void prep_wb(const us* __restrict__ wt2,
                                               const float* __restrict__ g,
                                               us* __restrict__ wbuf){
  size_t idx = (size_t)blockIdx.x * 256 + threadIdx.x;
  int d = (int)(idx % DDIM);
  size_t nd = idx / DDIM;
  int n = (int)(nd % DDIM);
  int b = (int)(nd / DDIM);
  float v = b2f(wt2[n * DDIM + d]) * g[(size_t)b * DDIM + d];
  wbuf[idx] = f2b(v);
}

// ---------------- combine: per batch — softmax + gating chain from matvecs
__global__ __launch_bounds__(256) void combine(
    const float* __restrict__ qwv, const float* __restrict__ qmv,
    const float* __restrict__ ksv,
    const float* __restrict__ bq, const float* __restrict__ bk,
    const float* __restrict__ w_g,
    const float* __restrict__ w_fc, const float* __restrict__ b_fc,
    const float* __restrict__ w_fc2, const float* __restrict__ b_fc2,
    float* __restrict__ g)
{
  __shared__ float smA[DDIM];
  __shared__ float smQM[DDIM];
  __shared__ float smKS[DDIM];
  __shared__ float tmat[12][DDIM];
  __shared__ float red[256];
  __shared__ float wbar[12];
  __shared__ float bbar;
  int b = blockIdx.x, t = threadIdx.x;

  // sum of w_g
  float sw = 0.f;
  for (int i = t; i < NP; i += 256) sw += w_g[i];
  red[t] = sw; __syncthreads();
  for (int off = 128; off; off >>= 1){
    if (t < off) red[t] += red[t + off];
    __syncthreads();
  }
  float sumwg = red[0];
  __syncthreads();

  for (int col = t; col < DDIM; col += 256){
    size_t o = (size_t)b * DDIM + col;
    smA[col]  = (qwv[o] + bq[col] * sumwg) * SCALEF;
    smQM[col] = qmv[o] * (1.0f / NP) + bq[col];
    smKS[col] = ksv[o] + (float)NP * bk[col];
  }
  __syncthreads();

  float lmax = -1e30f;
  for (int col = t; col < DDIM; col += 256) lmax = fmaxf(lmax, smA[col]);
  red[t] = lmax; __syncthreads();
  for (int off = 128; off; off >>= 1){
    if (t < off) red[t] = fmaxf(red[t], red[t + off]);
    __syncthreads();
  }
  float mx = red[0];
  __syncthreads();
  float lsum = 0.f;
  for (int col = t; col < DDIM; col += 256){
    float e = __expf(smA[col] - mx);
    smA[col] = e; lsum += e;
  }
  red[t] = lsum; __syncthreads();
  for (int off = 128; off; off >>= 1){
    if (t < off) red[t] += red[t + off];
    __syncthreads();
  }
  float inv = 1.0f / red[0];
  for (int col = t; col < DDIM; col += 256) smA[col] *= inv;

  if (t < 12){
    float s = 0.f;
    for (int j = 0; j < 12; ++j) s += w_fc2[t * 12 + j];
    wbar[t] = s * (1.0f / 12.0f);
  }
  if (t == 12){
    float s = 0.f;
    for (int j = 0; j < 12; ++j) s += b_fc2[j];
    bbar = s * (1.0f / 12.0f);
  }
  __syncthreads();
  for (int idx = t; idx < 12 * DDIM; idx += 256){
    int h = idx / DDIM, j = idx % DDIM;
    float s = b_fc[j];
    const float* qm = &smQM[h * 64];
    #pragma unroll 4
    for (int i = 0; i < 64; ++i) s += qm[i] * w_fc[i * DDIM + j];
    tmat[h][j] = 0.5f * s * (1.0f + erff(s * 0.70710678118654752f));
  }
  __syncthreads();
  for (int p = t; p < DDIM; p += 256){
    float s = bbar;
    #pragma unroll
    for (int m = 0; m < 12; ++m){
      int f = p * 12 + m;                 // torch reshape (b,12,768)->(b,768,12)
      s += tmat[f / DDIM][f % DDIM] * wbar[m];
    }
    float dv = 1.0f / (1.0f + __expf(-s));
    g[(size_t)b * DDIM + p] = smA[p] * smKS[p] * dv;
  }
}

// ---------------- GEMM2: out = k @ (g-scaled w_proj) + b_proj + layernorm(k)
__global__ __launch_bounds__(512, 2) void gemm_out(
    const us* __restrict__ kin, const us* __restrict__ wbuf,
    const float2* __restrict__ rstats,
    const float* __restrict__ bp, const float* __restrict__ gamma,
    const float* __restrict__ beta,
    float* __restrict__ out)
{
  extern __shared__ us lds[];
  int bid = blockIdx.x;
  int swz = (bid & 7) * ((int)gridDim.x >> 3) + (bid >> 3);
  int bn = swz % 3, bm = swz / 3;
  int m0 = bm * 256, n0 = bn * 256;
  int t = threadIdx.x;
  int b = m0 >> 12;

  f32x4 acc[4][4][2] = {};
  gemm256_core(kin + (size_t)m0 * DDIM,
               wbuf + (size_t)b * DDIM * DDIM + (size_t)n0 * DDIM, lds, t, acc);

  int wave = t >> 6, lane = t & 63;
  int wr = wave >> 2, wc = wave & 3, lr = lane & 15, lh = lane >> 4;

  // stage kin 256x256 tile (swizzled source cells, linear LDS dest)
  #pragma unroll
  for (int j = 0; j < 16; ++j){
    int row = j*16 + (t >> 5);
    const us* src = kin + (size_t)(m0 + row) * DDIM + n0 + (((t & 31) ^ (row & 7)) << 3);
    gl2lds16(src, lds + j*4096 + (wave << 9));
  }
  float2 st2[2][4];
  #pragma unroll
  for (int qm = 0; qm < 2; ++qm)
    #pragma unroll
    for (int fm = 0; fm < 4; ++fm)
      st2[qm][fm] = rstats[m0 + qm*128 + wr*64 + fm*16 + lr];
  asm volatile("s_waitcnt vmcnt(0)" ::: "memory");
  __syncthreads();

  #pragma unroll
  for (int p = 0; p < 4; ++p){
    int qm = p >> 1, qn = p & 1;
    #pragma unroll
    for (int fn = 0; fn < 2; ++fn){
      int col = qn*128 + wc*32 + fn*16 + lh*4;
      float4 bpv = *reinterpret_cast<const float4*>(&bp[n0 + col]);
      float4 gmv = *reinterpret_cast<const float4*>(&gamma[n0 + col]);
      float4 btv = *reinterpret_cast<const float4*>(&beta[n0 + col]);
      #pragma unroll
      for (int fm = 0; fm < 4; ++fm){
        int row = qm*128 + wr*64 + fm*16 + lr;
        uint2 kw = *reinterpret_cast<const uint2*>(&lds[row*256 + (col ^ ((row & 7) << 3))]);
        float2 st = st2[qm][fm];
        acc[p][fm][fn][0] += bpv.x + (b2f_lo(kw.x) - st.x) * st.y * gmv.x + btv.x;
        acc[p][fm][fn][1] += bpv.y + (b2f_hi(kw.x) - st.x) * st.y * gmv.y + btv.y;
        acc[p][fm][fn][2] += bpv.z + (b2f_lo(kw.y) - st.x) * st.y * gmv.z + btv.z;
        acc[p][fm][fn][3] += bpv.w + (b2f_hi(kw.y) - st.x) * st.y * gmv.w + btv.w;
      }
    }
  }
  __syncthreads();

  float* fb = reinterpret_cast<float*>(lds);   // [256][128] f32 = 128 KB
  #pragma unroll
  for (int h = 0; h < 2; ++h){
    #pragma unroll
    for (int qm2 = 0; qm2 < 2; ++qm2){
      int p = qm2*2 + h;
      #pragma unroll
      for (int fm = 0; fm < 4; ++fm){
        int row = qm2*128 + wr*64 + fm*16 + lr;
        #pragma unroll
        for (int fn = 0; fn < 2; ++fn){
          int c = wc*32 + fn*16 + lh*4;
          *reinterpret_cast<f32x4*>(&fb[row*128 + (c ^ ((row & 7) << 2))]) = acc[p][fm][fn];
        }
      }
    }
    __syncthreads();
    #pragma unroll
    for (int s = 0; s < 16; ++s){
      int u = s*512 + t;
      int row = u >> 5, c4 = u & 31;
      float4 vv = *reinterpret_cast<const float4*>(&fb[row*128 + ((c4 ^ (row & 7)) << 2)]);
      *reinterpret_cast<float4*>(&out[(size_t)(m0 + row) * DDIM + n0 + h*128 + c4*4]) = vv;
    }
    __syncthreads();
  }
}

extern "C" void kernel_launch(void* const* d_in, const int* in_sizes, int n_in,
                              void* d_out, int out_size, void* d_ws, size_t ws_size,
                              hipStream_t stream)
{
  const float* x      = (const float*)d_in[0];
  const float* wq     = (const float*)d_in[1];
  const float* bq     = (const float*)d_in[2];
  const float* wk     = (const float*)d_in[3];
  const float* bk     = (const float*)d_in[4];
  const float* w_g    = (const float*)d_in[5];
  const float* w_fc   = (const float*)d_in[6];
  const float* b_fc   = (const float*)d_in[7];
  const float* w_fc2  = (const float*)d_in[8];
  const float* b_fc2  = (const float*)d_in[9];
  const float* w_proj = (const float*)d_in[10];
  const float* b_proj = (const float*)d_in[11];
  const float* gamma  = (const float*)d_in[12];
  const float* beta   = (const float*)d_in[13];
  float* out = (float*)d_out;

  char* ws = (char*)d_ws;
  us*     xb    = (us*)(ws);                       // 100,663,296 B
  us*     kbuf  = (us*)(ws + 100663296);           // 100,663,296 B
  us*     wtk   = (us*)(ws + 201326592);           //   1,179,648 B
  us*     wt2   = (us*)(ws + 202506240);           //   1,179,648 B
  us*     wbuf  = (us*)(ws + 203685888);           //  18,874,368 B
  float*  xwp   = (float*)(ws + 222560256);        //   1,572,864 B
  float*  xsp   = (float*)(ws + 224133120);        //   1,572,864 B
  float*  lnS   = (float*)(ws + 225705984);        //     786,432 B
  float*  lnQ   = (float*)(ws + 226492416);        //     786,432 B
  float*  g     = (float*)(ws + 227278848);        //      49,152 B
  float2* rstat = (float2*)(ws + 227328000);       //     524,288 B
  float*  qwv   = (float*)(ws + 227852288);        //      49,152 B
  float*  qmv   = (float*)(ws + 227901440);        //      49,152 B
  float*  ksv   = (float*)(ws + 227950592);        //      49,152 B (~217.4 MiB)

  convert_x<<<dim3(MTOT / 128), dim3(384), 0, stream>>>(x, w_g, xb, xwp, xsp);
  prep_w<<<dim3(2 * DDIM * DDIM / 256), dim3(256), 0, stream>>>(wk, w_proj, wtk, wt2);
  xmv<<<dim3(NB * 6), dim3(256), 0, stream>>>(xwp, xsp, wq, wk, qwv, qmv, ksv);
  gemm_k<<<dim3((MTOT / 256) * 3), dim3(512), 131072, stream>>>(
      xb, wtk, bk, kbuf, lnS, lnQ);
  ln_reduce<<<dim3(MTOT / 256), dim3(256), 0, stream>>>(lnS, lnQ, rstat);
  combine<<<dim3(NB), dim3(256), 0, stream>>>(
      qwv, qmv, ksv, bq, bk, w_g, w_fc, b_fc, w_fc2, b_fc2, g);
  prep_wb<<<dim3(NB * DDIM * DDIM / 256), dim3(256), 0, stream>>>(wt2, g, wbuf);
  gemm_out<<<dim3((MTOT / 256) * 3), dim3(512), 131072, stream>>>(
      kbuf, wbuf, rstat, b_proj, gamma, beta, out);
}